// Round 5
// baseline (497.466 us; speedup 1.0000x reference)
//
#include <hip/hip_runtime.h>
#include <math.h>

// Problem constants (SphericalNSS_70909910057171): B=16, H=1024, W=2048, F=64
#define B_ 16
#define H_ 1024
#define W_ 2048
#define F_ 64
#define HW_ ((size_t)H_ * (size_t)W_)   // 2,097,152 elements per batch
#define CHUNKS 64                        // stage-1 chunks per batch
#define CHUNK_ELEMS 32768                // HW_/CHUNKS
#define EPS_ 1e-5
#define STATS_BLOCKS (B_ * CHUNKS)       // 1024
#define ROW_BLOCKS   (B_ * F_)           // 1024
#define TOTAL_BLOCKS (STATS_BLOCKS + ROW_BLOCKS)

typedef float vfloat4 __attribute__((ext_vector_type(4)));  // native clang vector (nontemporal-ok)

__device__ inline float wave_reduce_f(float v) {
#pragma unroll
    for (int o = 32; o > 0; o >>= 1) v += __shfl_down(v, o, 64);
    return v;
}

// ---------------- Single fused kernel --------------------------------------
// grid = 2048 blocks of 256 threads.
// Blocks [0,1024): per-batch sum/sumsq over a 32768-elem chunk (BW-bound).
// Blocks [1024,2048): per-(b,f) fixation-row dot partials (latency-bound,
// hidden under the stats blocks' HBM time).
// Last block to finish (device-scope counter) runs the fp64 final combine.
__global__ __launch_bounds__(256) void k_all(const float* __restrict__ y,
                                             const float* __restrict__ fix,
                                             const float* __restrict__ kern,
                                             const int* __restrict__ klen_arr,
                                             int Kmax,
                                             float* __restrict__ sumPart,
                                             float* __restrict__ sqPart,
                                             float* __restrict__ rowS0,
                                             float* __restrict__ rowS1,
                                             int* __restrict__ counter,
                                             float* __restrict__ out) {
    const int t = threadIdx.x;
    __shared__ float r0[4], r1[4];
    __shared__ int sy[F_], sleft[F_], sklen[F_];
    __shared__ int flist[F_];
    __shared__ int nlist;
    __shared__ int isLast;

    if (blockIdx.x < STATS_BLOCKS) {
        // ---------------- stats path ----------------
        const int blk = blockIdx.x;
        const int b = blk >> 6;     // / CHUNKS
        const int c = blk & 63;     // % CHUNKS
        const vfloat4* p4 = (const vfloat4*)(y + (size_t)b * HW_ + (size_t)c * CHUNK_ELEMS);
        float s = 0.f, q = 0.f;
#pragma unroll 8
        for (int i = 0; i < 32; ++i) {
            vfloat4 v = __builtin_nontemporal_load(&p4[t + i * 256]);
            s += (v.x + v.y) + (v.z + v.w);
            q += (v.x * v.x + v.y * v.y) + (v.z * v.z + v.w * v.w);
        }
        s = wave_reduce_f(s);
        q = wave_reduce_f(q);
        const int wave = t >> 6, lane = t & 63;
        if (lane == 0) { r0[wave] = s; r1[wave] = q; }
        __syncthreads();
        if (t == 0) {
            sumPart[blk] = (r0[0] + r0[1]) + (r0[2] + r0[3]);
            sqPart[blk]  = (r1[0] + r1[1]) + (r1[2] + r1[3]);
        }
    } else {
        // ---------------- rows path ----------------
        // Block (b,f) is active iff f is the FIRST fixation in batch b landing
        // on its row y; it resolves the FINAL row (latest covering fixation
        // wins = sequential-overwrite semantics) and computes
        // S0 = sum(row), S1 = dot(row, y_pred[b,y,:]). Inactive blocks write 0.
        const int blk = blockIdx.x - STATS_BLOCKS;
        const int b = blk >> 6;     // / F_
        const int f = blk & 63;     // % F_

        if (t < F_) {
            float fx = fix[((size_t)b * F_ + t) * 2 + 0];
            float fy = fix[((size_t)b * F_ + t) * 2 + 1];
            int x  = (int)rintf(fx * (float)(W_ - 1));  // round-half-even, matches jnp.rint
            int yy = (int)rintf(fy * (float)(H_ - 1));
            int kl = klen_arr[yy];
            sy[t] = yy;
            sklen[t] = kl;
            sleft[t] = x - (kl >> 1);
        }
        __syncthreads();

        const int yf = sy[f];
        bool active = true;
        for (int f2 = 0; f2 < f; ++f2) if (sy[f2] == yf) { active = false; break; }

        if (t == 0) {
            int n = 0;
            for (int f2 = F_ - 1; f2 >= 0; --f2) if (sy[f2] == yf) flist[n++] = f2;
            nlist = n;
        }
        __syncthreads();

        float s0 = 0.f, s1 = 0.f;
        if (active) {
            const bool pole = (yf == 0) || (yf == H_ - 1);
            const float* yrow = y + (size_t)b * HW_ + (size_t)yf * W_;
            const float* krow = kern + (size_t)yf * (size_t)Kmax;
            const int n = nlist;
            for (int p = t; p < W_; p += 256) {
                float val = 0.f;
                if (pole) {
                    val = 1.f;
                } else {
                    for (int j = 0; j < n; ++j) {
                        int f2 = flist[j];
                        int k = (p - sleft[f2]) & (W_ - 1);  // circular, W is pow2
                        if (k < sklen[f2]) { val = krow[k]; break; }
                    }
                }
                s0 += val;
                s1 += val * yrow[p];
            }
        }
        s0 = wave_reduce_f(s0);
        s1 = wave_reduce_f(s1);
        const int wave = t >> 6, lane = t & 63;
        if (lane == 0) { r0[wave] = s0; r1[wave] = s1; }
        __syncthreads();
        if (t == 0) {
            rowS0[blk] = (r0[0] + r0[1]) + (r0[2] + r0[3]);
            rowS1[blk] = (r1[0] + r1[1]) + (r1[2] + r1[3]);
        }
    }

    // ---------------- completion detection (device scope, cross-XCD) -------
    __threadfence();   // release: partials visible device-wide before count
    if (t == 0) {
        int old = __hip_atomic_fetch_add(counter, 1, __ATOMIC_ACQ_REL,
                                         __HIP_MEMORY_SCOPE_AGENT);
        isLast = (old == TOTAL_BLOCKS - 1);
    }
    __syncthreads();
    if (!isLast) return;
    __threadfence();   // acquire: see all other blocks' partials

    // ---------------- final combine (fp64, parallel, deterministic) --------
    // thread t: batch b = t>>4, slice j = t&15; 4 consecutive entries each.
    {
        const int b = t >> 4, j = t & 15;
        __shared__ double lS[256], lQ[256], lR0[256], lR1[256];
        __shared__ double nssArr[B_];

        double S = 0.0, Q = 0.0, R0 = 0.0, R1 = 0.0;
#pragma unroll
        for (int i = 0; i < 4; ++i) {
            int idx = b * 64 + j * 4 + i;   // CHUNKS==64 partials/batch; F_==64 rows/batch
            S  += (double)sumPart[idx];
            Q  += (double)sqPart[idx];
            R0 += (double)rowS0[idx];
            R1 += (double)rowS1[idx];
        }
        lS[t] = S; lQ[t] = Q; lR0[t] = R0; lR1[t] = R1;
        __syncthreads();

        if (j == 0) {
            double sS = 0.0, sQ = 0.0, sR0 = 0.0, sR1 = 0.0;
#pragma unroll
            for (int i = 0; i < 16; ++i) {
                sS += lS[t + i]; sQ += lQ[t + i]; sR0 += lR0[t + i]; sR1 += lR1[t + i];
            }
            const double N = (double)HW_;
            double mean = sS / N;
            double var = (sQ - sS * sS / N) / (N - 1.0);   // unbiased (ddof=1)
            double sd = sqrt(var);
            double denom = sd + (sd < EPS_ ? EPS_ : 0.0);
            nssArr[b] = (sR1 - mean * sR0) / denom / (double)F_;
        }
        __syncthreads();
        if (t == 0) {
            double acc = 0.0;
#pragma unroll
            for (int i = 0; i < B_; ++i) acc += nssArr[i];
            out[0] = (float)(acc / (double)B_);
        }
    }
}

extern "C" void kernel_launch(void* const* d_in, const int* in_sizes, int n_in,
                              void* d_out, int out_size, void* d_ws, size_t ws_size,
                              hipStream_t stream) {
    const float* y    = (const float*)d_in[0];   // [B,1,H,W] f32
    const float* fix  = (const float*)d_in[1];   // [B,F,2]  f32
    const float* kern = (const float*)d_in[2];   // [H,Kmax] f32
    const int*   kl   = (const int*)d_in[3];     // [H]      i32
    const int Kmax = in_sizes[2] / H_;

    float* ws = (float*)d_ws;
    float* sumPart = ws;                         // B_*CHUNKS = 1024
    float* sqPart  = ws + STATS_BLOCKS;          // 1024
    float* rowS0   = ws + 2 * STATS_BLOCKS;      // B_*F_ = 1024
    float* rowS1   = rowS0 + ROW_BLOCKS;         // 1024
    int*   counter = (int*)(ws + 2 * STATS_BLOCKS + 2 * ROW_BLOCKS);  // 1 int, 16B-aligned region
    float* out = (float*)d_out;

    // zero the completion counter (graph-capturable async memset node)
    hipMemsetAsync(counter, 0, sizeof(int), stream);
    hipLaunchKernelGGL(k_all, dim3(TOTAL_BLOCKS), dim3(256), 0, stream,
                       y, fix, kern, kl, Kmax, sumPart, sqPart, rowS0, rowS1,
                       counter, out);
}

// Round 6
// 205.263 us; speedup vs baseline: 2.4235x; 2.4235x over previous
//
#include <hip/hip_runtime.h>
#include <math.h>

// Problem constants (SphericalNSS_70909910057171): B=16, H=1024, W=2048, F=64
#define B_ 16
#define H_ 1024
#define W_ 2048
#define F_ 64
#define HW_ ((size_t)H_ * (size_t)W_)   // 2,097,152 elements per batch
#define CHUNKS 64                        // stage-1 chunks per batch
#define CHUNK_ELEMS 32768                // HW_/CHUNKS
#define EPS_ 1e-5
#define STATS_BLOCKS (B_ * CHUNKS)       // 1024
#define ROW_BLOCKS   (B_ * F_)           // 1024

typedef float vfloat4 __attribute__((ext_vector_type(4)));

__device__ inline float wave_reduce_f(float v) {
#pragma unroll
    for (int o = 32; o > 0; o >>= 1) v += __shfl_down(v, o, 64);
    return v;
}

// ---------------- Fused kernel: stats chunks + fixation rows --------------
// grid = STATS_BLOCKS + ROW_BLOCKS = 2048 blocks of 256 threads.
// Blocks [0,1024): per-batch sum/sumsq over a 32768-elem chunk (BW-bound;
// plain loads — y is partially L3-resident from the harness restore, nt hint
// measured counterproductive-or-neutral, R5 FETCH=69.6MB of 134MB).
// Blocks [1024,2048): per-(b,f) fixation-row dot partials (latency-bound,
// hidden under the stats blocks' HBM time).
// NOTE (R5 post-mortem): do NOT fuse the final combine into this kernel —
// per-block agent-scope fence/acq-rel atomics cost ~150ns each of serialized
// L2 wb/inv on multi-XCD gfx950 (2048 blocks -> +300us). The kernel boundary
// provides cross-XCD visibility once, for free.
__global__ __launch_bounds__(256) void k_main(const float* __restrict__ y,
                                              const float* __restrict__ fix,
                                              const float* __restrict__ kern,
                                              const int* __restrict__ klen_arr,
                                              int Kmax,
                                              float* __restrict__ sumPart,
                                              float* __restrict__ sqPart,
                                              float* __restrict__ rowS0,
                                              float* __restrict__ rowS1) {
    const int t = threadIdx.x;
    __shared__ float r0[4], r1[4];
    __shared__ int sy[F_], sleft[F_], sklen[F_];
    __shared__ int flist[F_];
    __shared__ int nlist;

    if (blockIdx.x < STATS_BLOCKS) {
        // ---------------- stats path ----------------
        const int blk = blockIdx.x;
        const int b = blk >> 6;     // / CHUNKS
        const int c = blk & 63;     // % CHUNKS
        const vfloat4* p4 = (const vfloat4*)(y + (size_t)b * HW_ + (size_t)c * CHUNK_ELEMS);
        float s = 0.f, q = 0.f;
#pragma unroll 8
        for (int i = 0; i < 32; ++i) {
            vfloat4 v = p4[t + i * 256];
            s += (v.x + v.y) + (v.z + v.w);
            q += (v.x * v.x + v.y * v.y) + (v.z * v.z + v.w * v.w);
        }
        s = wave_reduce_f(s);
        q = wave_reduce_f(q);
        const int wave = t >> 6, lane = t & 63;
        if (lane == 0) { r0[wave] = s; r1[wave] = q; }
        __syncthreads();
        if (t == 0) {
            sumPart[blk] = (r0[0] + r0[1]) + (r0[2] + r0[3]);
            sqPart[blk]  = (r1[0] + r1[1]) + (r1[2] + r1[3]);
        }
    } else {
        // ---------------- rows path ----------------
        // Block (b,f) is active iff f is the FIRST fixation in batch b landing
        // on its row y; it resolves the FINAL row (latest covering fixation
        // wins = sequential-overwrite semantics) and computes
        // S0 = sum(row), S1 = dot(row, y_pred[b,y,:]). Inactive blocks write 0.
        const int blk = blockIdx.x - STATS_BLOCKS;
        const int b = blk >> 6;     // / F_
        const int f = blk & 63;     // % F_

        if (t < F_) {
            float fx = fix[((size_t)b * F_ + t) * 2 + 0];
            float fy = fix[((size_t)b * F_ + t) * 2 + 1];
            int x  = (int)rintf(fx * (float)(W_ - 1));  // round-half-even, matches jnp.rint
            int yy = (int)rintf(fy * (float)(H_ - 1));
            int kl = klen_arr[yy];
            sy[t] = yy;
            sklen[t] = kl;
            sleft[t] = x - (kl >> 1);
        }
        __syncthreads();

        const int yf = sy[f];
        bool active = true;
        for (int f2 = 0; f2 < f; ++f2) if (sy[f2] == yf) { active = false; break; }

        if (t == 0) {
            int n = 0;
            for (int f2 = F_ - 1; f2 >= 0; --f2) if (sy[f2] == yf) flist[n++] = f2;
            nlist = n;
        }
        __syncthreads();

        float s0 = 0.f, s1 = 0.f;
        if (active) {
            const bool pole = (yf == 0) || (yf == H_ - 1);
            const float* yrow = y + (size_t)b * HW_ + (size_t)yf * W_;
            const float* krow = kern + (size_t)yf * (size_t)Kmax;
            const int n = nlist;
            for (int p = t; p < W_; p += 256) {
                float val = 0.f;
                if (pole) {
                    val = 1.f;
                } else {
                    for (int j = 0; j < n; ++j) {
                        int f2 = flist[j];
                        int k = (p - sleft[f2]) & (W_ - 1);  // circular, W is pow2
                        if (k < sklen[f2]) { val = krow[k]; break; }
                    }
                }
                s0 += val;
                s1 += val * yrow[p];
            }
        }
        s0 = wave_reduce_f(s0);
        s1 = wave_reduce_f(s1);
        const int wave = t >> 6, lane = t & 63;
        if (lane == 0) { r0[wave] = s0; r1[wave] = s1; }
        __syncthreads();
        if (t == 0) {
            rowS0[blk] = (r0[0] + r0[1]) + (r0[2] + r0[3]);
            rowS1[blk] = (r1[0] + r1[1]) + (r1[2] + r1[3]);
        }
    }
}

// ---------------- Kernel 2: final combine (fp64, parallel, deterministic) ----
// 256 threads: thread t handles batch b = t>>4, partial-slice j = t&15.
__global__ __launch_bounds__(256) void k_final(const float* __restrict__ sumPart,
                                               const float* __restrict__ sqPart,
                                               const float* __restrict__ rowS0,
                                               const float* __restrict__ rowS1,
                                               float* __restrict__ out) {
    const int t = threadIdx.x;
    const int b = t >> 4, j = t & 15;
    __shared__ double lS[256], lQ[256], lR0[256], lR1[256];
    __shared__ double nssArr[B_];

    double S = 0.0, Q = 0.0, R0 = 0.0, R1 = 0.0;
#pragma unroll
    for (int i = 0; i < 4; ++i) {
        int idx = b * 64 + j * 4 + i;   // CHUNKS==64 partials/batch; F_==64 rows/batch
        S  += (double)sumPart[idx];
        Q  += (double)sqPart[idx];
        R0 += (double)rowS0[idx];
        R1 += (double)rowS1[idx];
    }
    lS[t] = S; lQ[t] = Q; lR0[t] = R0; lR1[t] = R1;
    __syncthreads();

    if (j == 0) {
        double sS = 0.0, sQ = 0.0, sR0 = 0.0, sR1 = 0.0;
#pragma unroll
        for (int i = 0; i < 16; ++i) {
            sS += lS[t + i]; sQ += lQ[t + i]; sR0 += lR0[t + i]; sR1 += lR1[t + i];
        }
        const double N = (double)HW_;
        double mean = sS / N;
        double var = (sQ - sS * sS / N) / (N - 1.0);   // unbiased (ddof=1)
        double sd = sqrt(var);
        double denom = sd + (sd < EPS_ ? EPS_ : 0.0);
        nssArr[b] = (sR1 - mean * sR0) / denom / (double)F_;
    }
    __syncthreads();
    if (t == 0) {
        double acc = 0.0;
#pragma unroll
        for (int i = 0; i < B_; ++i) acc += nssArr[i];
        out[0] = (float)(acc / (double)B_);
    }
}

extern "C" void kernel_launch(void* const* d_in, const int* in_sizes, int n_in,
                              void* d_out, int out_size, void* d_ws, size_t ws_size,
                              hipStream_t stream) {
    const float* y    = (const float*)d_in[0];   // [B,1,H,W] f32
    const float* fix  = (const float*)d_in[1];   // [B,F,2]  f32
    const float* kern = (const float*)d_in[2];   // [H,Kmax] f32
    const int*   kl   = (const int*)d_in[3];     // [H]      i32
    const int Kmax = in_sizes[2] / H_;

    float* ws = (float*)d_ws;
    float* sumPart = ws;                         // B_*CHUNKS = 1024
    float* sqPart  = ws + STATS_BLOCKS;          // 1024
    float* rowS0   = ws + 2 * STATS_BLOCKS;      // B_*F_ = 1024
    float* rowS1   = rowS0 + ROW_BLOCKS;         // 1024
    float* out = (float*)d_out;

    hipLaunchKernelGGL(k_main, dim3(STATS_BLOCKS + ROW_BLOCKS), dim3(256), 0, stream,
                       y, fix, kern, kl, Kmax, sumPart, sqPart, rowS0, rowS1);
    hipLaunchKernelGGL(k_final, dim3(1), dim3(256), 0, stream,
                       sumPart, sqPart, rowS0, rowS1, out);
}

// Round 7
// 194.325 us; speedup vs baseline: 2.5600x; 1.0563x over previous
//
#include <hip/hip_runtime.h>
#include <math.h>

// Problem constants (SphericalNSS_70909910057171): B=16, H=1024, W=2048, F=64
#define B_ 16
#define H_ 1024
#define W_ 2048
#define F_ 64
#define HW_ ((size_t)H_ * (size_t)W_)   // 2,097,152 elements per batch
#define CHUNKS 64                        // stage-1 chunks per batch
#define CHUNK_ELEMS 32768                // HW_/CHUNKS
#define EPS_ 1e-5
#define STATS_BLOCKS (B_ * CHUNKS)       // 1024
#define ROW_BLOCKS   (B_ * F_)           // 1024

typedef float vfloat4 __attribute__((ext_vector_type(4)));  // native clang vector (nontemporal-ok)

__device__ inline float wave_reduce_f(float v) {
#pragma unroll
    for (int o = 32; o > 0; o >>= 1) v += __shfl_down(v, o, 64);
    return v;
}

// ---------------- Fused kernel: stats chunks + fixation rows --------------
// grid = STATS_BLOCKS + ROW_BLOCKS = 2048 blocks of 256 threads.
// Blocks [0,1024): per-batch sum/sumsq over a 32768-elem chunk (BW-bound).
//   NONTEMPORAL loads are a measured WIN here (R4 194.9 vs R6-plain 205.3 µs):
//   y is partially L3-resident from the harness restore (R5 FETCH=69.6MB of
//   134MB); nt keeps the stream-once fill at low replacement priority so it
//   doesn't evict the warmed lines mid-kernel.
// Blocks [1024,2048): per-(b,f) fixation-row dot partials (latency-bound,
// hidden under the stats blocks' HBM time).
// NOTE (R5 post-mortem): do NOT fuse the final combine into this kernel —
// per-block agent-scope fence/acq-rel atomics cost ~150ns each of serialized
// L2 wb/inv on multi-XCD gfx950 (2048 blocks -> +300us). The kernel boundary
// provides cross-XCD visibility once, for free.
__global__ __launch_bounds__(256) void k_main(const float* __restrict__ y,
                                              const float* __restrict__ fix,
                                              const float* __restrict__ kern,
                                              const int* __restrict__ klen_arr,
                                              int Kmax,
                                              float* __restrict__ sumPart,
                                              float* __restrict__ sqPart,
                                              float* __restrict__ rowS0,
                                              float* __restrict__ rowS1) {
    const int t = threadIdx.x;
    __shared__ float r0[4], r1[4];
    __shared__ int sy[F_], sleft[F_], sklen[F_];
    __shared__ int flist[F_];
    __shared__ int nlist;

    if (blockIdx.x < STATS_BLOCKS) {
        // ---------------- stats path ----------------
        const int blk = blockIdx.x;
        const int b = blk >> 6;     // / CHUNKS
        const int c = blk & 63;     // % CHUNKS
        const vfloat4* p4 = (const vfloat4*)(y + (size_t)b * HW_ + (size_t)c * CHUNK_ELEMS);
        float s = 0.f, q = 0.f;
#pragma unroll 8
        for (int i = 0; i < 32; ++i) {
            vfloat4 v = __builtin_nontemporal_load(&p4[t + i * 256]);
            s += (v.x + v.y) + (v.z + v.w);
            q += (v.x * v.x + v.y * v.y) + (v.z * v.z + v.w * v.w);
        }
        s = wave_reduce_f(s);
        q = wave_reduce_f(q);
        const int wave = t >> 6, lane = t & 63;
        if (lane == 0) { r0[wave] = s; r1[wave] = q; }
        __syncthreads();
        if (t == 0) {
            sumPart[blk] = (r0[0] + r0[1]) + (r0[2] + r0[3]);
            sqPart[blk]  = (r1[0] + r1[1]) + (r1[2] + r1[3]);
        }
    } else {
        // ---------------- rows path ----------------
        // Block (b,f) is active iff f is the FIRST fixation in batch b landing
        // on its row y; it resolves the FINAL row (latest covering fixation
        // wins = sequential-overwrite semantics) and computes
        // S0 = sum(row), S1 = dot(row, y_pred[b,y,:]). Inactive blocks write 0.
        const int blk = blockIdx.x - STATS_BLOCKS;
        const int b = blk >> 6;     // / F_
        const int f = blk & 63;     // % F_

        if (t < F_) {
            float fx = fix[((size_t)b * F_ + t) * 2 + 0];
            float fy = fix[((size_t)b * F_ + t) * 2 + 1];
            int x  = (int)rintf(fx * (float)(W_ - 1));  // round-half-even, matches jnp.rint
            int yy = (int)rintf(fy * (float)(H_ - 1));
            int kl = klen_arr[yy];
            sy[t] = yy;
            sklen[t] = kl;
            sleft[t] = x - (kl >> 1);
        }
        __syncthreads();

        const int yf = sy[f];
        bool active = true;
        for (int f2 = 0; f2 < f; ++f2) if (sy[f2] == yf) { active = false; break; }

        if (t == 0) {
            int n = 0;
            for (int f2 = F_ - 1; f2 >= 0; --f2) if (sy[f2] == yf) flist[n++] = f2;
            nlist = n;
        }
        __syncthreads();

        float s0 = 0.f, s1 = 0.f;
        if (active) {
            const bool pole = (yf == 0) || (yf == H_ - 1);
            const float* yrow = y + (size_t)b * HW_ + (size_t)yf * W_;
            const float* krow = kern + (size_t)yf * (size_t)Kmax;
            const int n = nlist;
            for (int p = t; p < W_; p += 256) {
                float val = 0.f;
                if (pole) {
                    val = 1.f;
                } else {
                    for (int j = 0; j < n; ++j) {
                        int f2 = flist[j];
                        int k = (p - sleft[f2]) & (W_ - 1);  // circular, W is pow2
                        if (k < sklen[f2]) { val = krow[k]; break; }
                    }
                }
                s0 += val;
                s1 += val * yrow[p];
            }
        }
        s0 = wave_reduce_f(s0);
        s1 = wave_reduce_f(s1);
        const int wave = t >> 6, lane = t & 63;
        if (lane == 0) { r0[wave] = s0; r1[wave] = s1; }
        __syncthreads();
        if (t == 0) {
            rowS0[blk] = (r0[0] + r0[1]) + (r0[2] + r0[3]);
            rowS1[blk] = (r1[0] + r1[1]) + (r1[2] + r1[3]);
        }
    }
}

// ---------------- Kernel 2: final combine (fp64, parallel, deterministic) ----
// 256 threads: thread t handles batch b = t>>4, partial-slice j = t&15.
__global__ __launch_bounds__(256) void k_final(const float* __restrict__ sumPart,
                                               const float* __restrict__ sqPart,
                                               const float* __restrict__ rowS0,
                                               const float* __restrict__ rowS1,
                                               float* __restrict__ out) {
    const int t = threadIdx.x;
    const int b = t >> 4, j = t & 15;
    __shared__ double lS[256], lQ[256], lR0[256], lR1[256];
    __shared__ double nssArr[B_];

    double S = 0.0, Q = 0.0, R0 = 0.0, R1 = 0.0;
#pragma unroll
    for (int i = 0; i < 4; ++i) {
        int idx = b * 64 + j * 4 + i;   // CHUNKS==64 partials/batch; F_==64 rows/batch
        S  += (double)sumPart[idx];
        Q  += (double)sqPart[idx];
        R0 += (double)rowS0[idx];
        R1 += (double)rowS1[idx];
    }
    lS[t] = S; lQ[t] = Q; lR0[t] = R0; lR1[t] = R1;
    __syncthreads();

    if (j == 0) {
        double sS = 0.0, sQ = 0.0, sR0 = 0.0, sR1 = 0.0;
#pragma unroll
        for (int i = 0; i < 16; ++i) {
            sS += lS[t + i]; sQ += lQ[t + i]; sR0 += lR0[t + i]; sR1 += lR1[t + i];
        }
        const double N = (double)HW_;
        double mean = sS / N;
        double var = (sQ - sS * sS / N) / (N - 1.0);   // unbiased (ddof=1)
        double sd = sqrt(var);
        double denom = sd + (sd < EPS_ ? EPS_ : 0.0);
        nssArr[b] = (sR1 - mean * sR0) / denom / (double)F_;
    }
    __syncthreads();
    if (t == 0) {
        double acc = 0.0;
#pragma unroll
        for (int i = 0; i < B_; ++i) acc += nssArr[i];
        out[0] = (float)(acc / (double)B_);
    }
}

extern "C" void kernel_launch(void* const* d_in, const int* in_sizes, int n_in,
                              void* d_out, int out_size, void* d_ws, size_t ws_size,
                              hipStream_t stream) {
    const float* y    = (const float*)d_in[0];   // [B,1,H,W] f32
    const float* fix  = (const float*)d_in[1];   // [B,F,2]  f32
    const float* kern = (const float*)d_in[2];   // [H,Kmax] f32
    const int*   kl   = (const int*)d_in[3];     // [H]      i32
    const int Kmax = in_sizes[2] / H_;

    float* ws = (float*)d_ws;
    float* sumPart = ws;                         // B_*CHUNKS = 1024
    float* sqPart  = ws + STATS_BLOCKS;          // 1024
    float* rowS0   = ws + 2 * STATS_BLOCKS;      // B_*F_ = 1024
    float* rowS1   = rowS0 + ROW_BLOCKS;         // 1024
    float* out = (float*)d_out;

    hipLaunchKernelGGL(k_main, dim3(STATS_BLOCKS + ROW_BLOCKS), dim3(256), 0, stream,
                       y, fix, kern, kl, Kmax, sumPart, sqPart, rowS0, rowS1);
    hipLaunchKernelGGL(k_final, dim3(1), dim3(256), 0, stream,
                       sumPart, sqPart, rowS0, rowS1, out);
}